// Round 9
// baseline (378.422 us; speedup 1.0000x reference)
//
#include <hip/hip_runtime.h>
#include <hip/hip_bf16.h>
#include <math.h>

#define NN   20000
#define NE   640000
#define HD   128
#define EDIM 16
#define KIN  273
#define P2   136      // LDS pitch (ushorts)

#define S_PWT   4096    // We1 tail:   1 kb x 8 nb x 512 (interleaved cols)
#define S_PWE1M 32768   // We1 main:   8 kb x 8 nb x 512 (interleaved cols)
#define S_PW4   16384   // We2/Wx1:    4 kb x 8 nb x 512 (interleaved cols)
#define S_PWH1  32768   // Wh1:        8 kb x 8 nb x 512 (identity cols)
#define S_PWH2  16384   // Wh2:        4 kb x 8 nb x 512 (identity cols)

typedef __bf16 bf16x8 __attribute__((ext_vector_type(8)));
typedef float  f32x4  __attribute__((ext_vector_type(4)));

__device__ __forceinline__ float silu_f(float v) {
    const float e = __expf(-v);
    return v * __builtin_amdgcn_rcpf(1.0f + e);
}
__device__ __forceinline__ float tanh_f(float s) {
    const float e = __expf(2.0f * s);
    return 1.0f - 2.0f * __builtin_amdgcn_rcpf(e + 1.0f);
}
__device__ __forceinline__ unsigned short f2bf(float f) {
    __bf16 b = (__bf16)f;
    return __builtin_bit_cast(unsigned short, b);
}
__device__ __forceinline__ float bf2f(unsigned short u) {
    __bf16 b = __builtin_bit_cast(__bf16, u);
    return (float)b;
}
__device__ __forceinline__ unsigned pack2bf(float a, float b) {
    return (unsigned)f2bf(a) | ((unsigned)f2bf(b) << 16);
}
// load 8 f32 and convert to a bf16x8 MFMA fragment (RNE, same as f2bf)
__device__ __forceinline__ bf16x8 ldcvt_bf8(const float* __restrict__ p) {
    const float4 v0 = ((const float4*)p)[0];
    const float4 v1 = ((const float4*)p)[1];
    bf16x8 av;
    av[0]=(__bf16)v0.x; av[1]=(__bf16)v0.y; av[2]=(__bf16)v0.z; av[3]=(__bf16)v0.w;
    av[4]=(__bf16)v1.x; av[5]=(__bf16)v1.y; av[6]=(__bf16)v1.z; av[7]=(__bf16)v1.w;
    return av;
}

// identity pack: tile (kb,nb): elem[lane*8+j] = W[kb*32+(lane>>4)*8+j][nb*16+(lane&15)]
__device__ __forceinline__ void pack_id(const float* __restrict__ W, int Kreal,
                                        unsigned short* __restrict__ P, int idx) {
    const int f = idx >> 9, r = idx & 511;
    const int lane = r >> 3, j = r & 7;
    const int kb = f >> 3, nb = f & 7;
    const int k = kb * 32 + (lane >> 4) * 8 + j;
    const int n = nb * 16 + (lane & 15);
    P[idx] = f2bf((k < Kreal) ? W[(size_t)k * HD + n] : 0.0f);
}
// interleaved pack: n = (nb>>1)*32 + 2*(lane&15) + (nb&1)
__device__ __forceinline__ void pack_il(const float* __restrict__ W, int Kreal,
                                        unsigned short* __restrict__ P, int idx) {
    const int f = idx >> 9, r = idx & 511;
    const int lane = r >> 3, j = r & 7;
    const int kb = f >> 3, nb = f & 7;
    const int k = kb * 32 + (lane >> 4) * 8 + j;
    const int n = (nb >> 1) * 32 + 2 * (lane & 15) + (nb & 1);
    P[idx] = f2bf((k < Kreal) ? W[(size_t)k * HD + n] : 0.0f);
}

// ===== prep: pack all weights + dst histogram =====
// r9: hb (h->bf16 cast) DELETED — pre/node convert f32 h in-register.
// prep is now packs (119K items) + histogram (640K) = 0.76M iterations
// (was 4.04M at r0, 1.40M after r6's memset consolidation).

__global__ void egnn_prep_kernel(
    const int* __restrict__ ei,
    const float* __restrict__ We1, const float* __restrict__ We2,
    const float* __restrict__ Wx1, const float* __restrict__ Wh1,
    const float* __restrict__ Wh2,
    unsigned short* __restrict__ PWt,  unsigned short* __restrict__ PWe1m,
    unsigned short* __restrict__ PWe2, unsigned short* __restrict__ PWx1,
    unsigned short* __restrict__ PWh1, unsigned short* __restrict__ PWh2,
    int* __restrict__ cnt)
{
    const size_t T1 = S_PWT, T2 = T1 + S_PWE1M, T3 = T2 + S_PW4;
    const size_t T4 = T3 + S_PW4, T5 = T4 + S_PWH1, T6 = T5 + S_PWH2;
    const size_t TOT = T6 + NE;
    const size_t stride = (size_t)gridDim.x * blockDim.x;
    for (size_t i = (size_t)blockIdx.x * blockDim.x + threadIdx.x; i < TOT; i += stride) {
        if (i < T1) {   // We1 tail (rows 256..272), interleaved cols, kb==0
            const int idx = (int)i;
            const int r = idx & 511, nb = idx >> 9;
            const int lane = r >> 3, j = r & 7;
            const int k = 256 + (lane >> 4) * 8 + j;
            const int n = (nb >> 1) * 32 + 2 * (lane & 15) + (nb & 1);
            PWt[idx] = f2bf((k < KIN) ? We1[(size_t)k * HD + n] : 0.0f);
            continue;
        }
        if (i < T2) { pack_il(We1, 256, PWe1m, (int)(i - T1)); continue; }
        if (i < T3) { pack_il(We2, HD, PWe2, (int)(i - T2)); continue; }
        if (i < T4) { pack_il(Wx1, HD, PWx1, (int)(i - T3)); continue; }
        if (i < T5) { pack_id(Wh1, 2 * HD, PWh1, (int)(i - T4)); continue; }
        if (i < T6) { pack_id(Wh2, HD, PWh2, (int)(i - T5)); continue; }
        atomicAdd(&cnt[ei[NE + (i - T6)]], 1);   // histogram
    }
}

// ====== preGEMM (blocks 0..624, 32 rows each) + scan (block 625) ======
// A-fragments converted from f32 h in-register (r9, hb deleted).
__global__ __launch_bounds__(256, 4) void egnn_pre_kernel(
    const float* __restrict__ h,
    const unsigned short* __restrict__ PWe1m, const float* __restrict__ be1,
    const int* __restrict__ cnt, int* __restrict__ cursor,
    unsigned short* __restrict__ preS, unsigned short* __restrict__ preD)
{
    const int t = threadIdx.x;
    if (blockIdx.x == 625) {        // exclusive scan of cnt -> cursor (SEG=79)
        __shared__ int ls[256];
        const int base = t * 79;
        int c[79];
        int s = 0;
        for (int i = 0; i < 79; ++i) {
            const int idx = base + i;
            c[i] = (idx < NN) ? cnt[idx] : 0;
            s += c[i];
        }
        ls[t] = s;
        __syncthreads();
        int v = s;
        for (int off = 1; off < 256; off <<= 1) {
            const int u = (t >= off) ? ls[t - off] : 0;
            __syncthreads();
            v += u;
            ls[t] = v;
            __syncthreads();
        }
        int run = v - s;
        for (int i = 0; i < 79; ++i) {
            const int idx = base + i;
            if (idx < NN) { cursor[idx] = run; run += c[i]; }
        }
        return;
    }
    // preS = h@We1[0:128]; preD = h@We1[128:256] + be1 (interleaved col order)
    const int n0 = blockIdx.x * 32;
    const int lane = t & 63, w = t >> 6;
    const int quad = lane >> 4, l16 = lane & 15;
    int arow[2];
    #pragma unroll
    for (int mb = 0; mb < 2; ++mb) arow[mb] = min(n0 + mb * 16 + l16, NN - 1);

    f32x4 accS[2][2], accD[2][2];
    #pragma unroll
    for (int mb = 0; mb < 2; ++mb)
        #pragma unroll
        for (int nt = 0; nt < 2; ++nt) {
            accS[mb][nt] = (f32x4){0.f,0.f,0.f,0.f};
            accD[mb][nt] = (f32x4){0.f,0.f,0.f,0.f};
        }
    #pragma unroll
    for (int kb = 0; kb < 4; ++kb) {
        bf16x8 a[2], bS[2], bD[2];
        #pragma unroll
        for (int mb = 0; mb < 2; ++mb)
            a[mb] = ldcvt_bf8(&h[(size_t)arow[mb] * HD + kb * 32 + quad * 8]);
        #pragma unroll
        for (int nt = 0; nt < 2; ++nt) {
            bS[nt] = *(const bf16x8*)&PWe1m[((kb * 8 + w * 2 + nt) * 64 + lane) * 8];
            bD[nt] = *(const bf16x8*)&PWe1m[(((4 + kb) * 8 + w * 2 + nt) * 64 + lane) * 8];
        }
        #pragma unroll
        for (int mb = 0; mb < 2; ++mb)
            #pragma unroll
            for (int nt = 0; nt < 2; ++nt) {
                accS[mb][nt] = __builtin_amdgcn_mfma_f32_16x16x32_bf16(
                    a[mb], bS[nt], accS[mb][nt], 0, 0, 0);
                accD[mb][nt] = __builtin_amdgcn_mfma_f32_16x16x32_bf16(
                    a[mb], bD[nt], accD[mb][nt], 0, 0, 0);
            }
    }
    const int cb = w * 32 + 2 * l16;
    const float2 b1 = *(const float2*)&be1[cb];
    #pragma unroll
    for (int mb = 0; mb < 2; ++mb)
        #pragma unroll
        for (int r = 0; r < 4; ++r) {
            const int n = n0 + mb * 16 + quad * 4 + r;
            if (n < NN) {
                *(unsigned*)&preS[(size_t)n * HD + cb] =
                    pack2bf(accS[mb][0][r], accS[mb][1][r]);
                *(unsigned*)&preD[(size_t)n * HD + cb] =
                    pack2bf(accD[mb][0][r] + b1.x, accD[mb][1][r] + b1.y);
            }
        }
}

// ============ perm ============
__global__ void egnn_perm_kernel(const int* __restrict__ ei,
                                 int* __restrict__ cursor, int* __restrict__ perm) {
    const int e = blockIdx.x * 256 + threadIdx.x;
    const int pos = atomicAdd(&cursor[ei[NE + e]], 1);
    perm[pos] = e;
}

// ===== edge kernel: r0 structure (gather preC, 6 blocks/CU, no swizzle,
// plain cached loads). A/B ledger:
//   r1 XCD swizzle      -> atomic fabric ping-pong (W 60->148MB)   REVERTED
//   r2 8 blocks/CU      -> L2 dst-window overflow (F+50,W+89MB)    REVERTED
//   r3 identity-MFMA    -> lost latency-hiding VALU, traffic up    REVERTED
//   r4 NT loads         -> killed line-granularity reuse (F+91MB)  REVERTED
// Kept: bias folds into MFMA C-init (numerics-neutral, no traffic delta).
// Edge run-to-run variance ~±7% at identical counters (r5 vs r6).
__global__ __launch_bounds__(256, 6) void egnn_edge_kernel(
    const unsigned short* __restrict__ preS, const unsigned short* __restrict__ preD,
    const float* __restrict__ x,
    const int* __restrict__ ei, const float* __restrict__ eattr,
    const int* __restrict__ perm,
    const unsigned short* __restrict__ PWt,
    const unsigned short* __restrict__ PWe2, const float* __restrict__ be2,
    const unsigned short* __restrict__ PWx1, const float* __restrict__ bx1,
    const float* __restrict__ Wx2, const float* __restrict__ bx2,
    float* __restrict__ msg_agg, float* __restrict__ coord_agg)
{
    __shared__ __align__(16) unsigned short buf[64 * P2];   // tail -> sT -> sM -> red
    __shared__ int   sE[64], sSrc[64], sDst[64];
    __shared__ float sDiff[64][3];
    __shared__ float sW[64];

    const int t  = threadIdx.x;
    const int e0 = blockIdx.x * 64;
    unsigned short* tail = buf;   // [64][32] in first 4 KB

    if (t < 64) {
        const int e = perm[e0 + t];
        sE[t] = e;
        const int s = ei[e];
        const int d = ei[NE + e];
        sSrc[t] = s; sDst[t] = d;
        const float dx = x[s*3+0] - x[d*3+0];
        const float dy = x[s*3+1] - x[d*3+1];
        const float dz = x[s*3+2] - x[d*3+2];
        sDiff[t][0] = dx; sDiff[t][1] = dy; sDiff[t][2] = dz;
        tail[t * 32 + 0] = f2bf((dx*dx + dy*dy + dz*dz) * 0.01f);
    }
    __syncthreads();

    const int lane = t & 63;
    const int w    = t >> 6;
    const int quad = lane >> 4;
    const int l16  = lane & 15;
    const int cb   = w * 32 + 2 * l16;

    // preC = preS[src] + preD[dst] (preD includes be1)
    f32x4 preC[4][2];
    #pragma unroll
    for (int mb = 0; mb < 4; ++mb)
        #pragma unroll
        for (int r = 0; r < 4; ++r) {
            const int row = mb * 16 + quad * 4 + r;
            const unsigned us = *(const unsigned*)&preS[(size_t)sSrc[row] * HD + cb];
            const unsigned ud = *(const unsigned*)&preD[(size_t)sDst[row] * HD + cb];
            preC[mb][0][r] = bf2f((unsigned short)(us & 0xffff)) +
                             bf2f((unsigned short)(ud & 0xffff));
            preC[mb][1][r] = bf2f((unsigned short)(us >> 16)) +
                             bf2f((unsigned short)(ud >> 16));
        }

    // tail cols 1..31
    {
        const int eL = t >> 2, q = t & 3;
        const int eG = sE[eL];
        #pragma unroll
        for (int jj = 0; jj < 8; ++jj) {
            const int col = q * 8 + jj;
            if (col == 0) continue;
            float v = 0.0f;
            if (col <= EDIM) v = eattr[(size_t)eG * EDIM + (col - 1)];
            tail[eL * 32 + col] = f2bf(v);
        }
    }
    __syncthreads();

    // GEMM1 (K=32 tail), C init = preC
    f32x4 acc1[4][2];
    {
        bf16x8 a[4], b[2];
        #pragma unroll
        for (int mb = 0; mb < 4; ++mb)
            a[mb] = *(const bf16x8*)&tail[(mb * 16 + l16) * 32 + quad * 8];
        #pragma unroll
        for (int nt = 0; nt < 2; ++nt)
            b[nt] = *(const bf16x8*)&PWt[((w * 2 + nt) * 64 + lane) * 8];
        #pragma unroll
        for (int mb = 0; mb < 4; ++mb)
            #pragma unroll
            for (int nt = 0; nt < 2; ++nt)
                acc1[mb][nt] = __builtin_amdgcn_mfma_f32_16x16x32_bf16(
                    a[mb], b[nt], preC[mb][nt], 0, 0, 0);
    }
    __syncthreads();   // all tail reads done -> buf reusable as sT

    #pragma unroll
    for (int mb = 0; mb < 4; ++mb)
        #pragma unroll
        for (int r = 0; r < 4; ++r) {
            const int row = mb * 16 + quad * 4 + r;
            *(unsigned*)&buf[row * P2 + cb] =
                pack2bf(silu_f(acc1[mb][0][r]), silu_f(acc1[mb][1][r]));
        }
    __syncthreads();

    // GEMM2: t1 @ We2  (be2 folded into C-init)
    const float2 b2 = *(const float2*)&be2[cb];
    f32x4 acc2[4][2];
    #pragma unroll
    for (int mb = 0; mb < 4; ++mb) {
        acc2[mb][0] = (f32x4){b2.x, b2.x, b2.x, b2.x};
        acc2[mb][1] = (f32x4){b2.y, b2.y, b2.y, b2.y};
    }
    #pragma unroll
    for (int kb = 0; kb < 4; ++kb) {
        bf16x8 a[4], b[2];
        #pragma unroll
        for (int mb = 0; mb < 4; ++mb)
            a[mb] = *(const bf16x8*)&buf[(mb * 16 + l16) * P2 + kb * 32 + quad * 8];
        #pragma unroll
        for (int nt = 0; nt < 2; ++nt)
            b[nt] = *(const bf16x8*)&PWe2[((kb * 8 + w * 2 + nt) * 64 + lane) * 8];
        #pragma unroll
        for (int mb = 0; mb < 4; ++mb)
            #pragma unroll
            for (int nt = 0; nt < 2; ++nt)
                acc2[mb][nt] = __builtin_amdgcn_mfma_f32_16x16x32_bf16(
                    a[mb], b[nt], acc2[mb][nt], 0, 0, 0);
    }
    __syncthreads();   // all sT reads done -> buf reusable as sM

    {
        #pragma unroll
        for (int mb = 0; mb < 4; ++mb)
            #pragma unroll
            for (int r = 0; r < 4; ++r) {
                const int row = mb * 16 + quad * 4 + r;
                *(unsigned*)&buf[row * P2 + cb] =
                    pack2bf(silu_f(acc2[mb][0][r]),
                            silu_f(acc2[mb][1][r]));
            }
    }
    __syncthreads();

    // msg: dst-sorted run reduction (reads buf as sM)
    {
        const int cp = t & 63;
        const int r0 = (t >> 6) * 16;
        float a0 = 0.0f, a1 = 0.0f;
        #pragma unroll 4
        for (int r = 0; r < 16; ++r) {
            const int row = r0 + r;
            const int d   = sDst[row];
            const unsigned u = *(const unsigned*)&buf[row * P2 + 2 * cp];
            a0 += bf2f((unsigned short)(u & 0xffff));
            a1 += bf2f((unsigned short)(u >> 16));
            const bool flush = (r == 15) || (sDst[row + 1] != d);
            if (flush) {
                atomicAdd(&msg_agg[(size_t)d * HD + 2 * cp], a0);
                atomicAdd(&msg_agg[(size_t)d * HD + 2 * cp + 1], a1);
                a0 = 0.0f; a1 = 0.0f;
            }
        }
    }

    // GEMM3: m @ Wx1 (reads buf as sM; bx1 folded into C-init)
    const float2 bx = *(const float2*)&bx1[cb];
    const float2 w2 = *(const float2*)&Wx2[cb];
    f32x4 acc3[4][2];
    #pragma unroll
    for (int mb = 0; mb < 4; ++mb) {
        acc3[mb][0] = (f32x4){bx.x, bx.x, bx.x, bx.x};
        acc3[mb][1] = (f32x4){bx.y, bx.y, bx.y, bx.y};
    }
    #pragma unroll
    for (int kb = 0; kb < 4; ++kb) {
        bf16x8 a[4], b[2];
        #pragma unroll
        for (int mb = 0; mb < 4; ++mb)
            a[mb] = *(const bf16x8*)&buf[(mb * 16 + l16) * P2 + kb * 32 + quad * 8];
        #pragma unroll
        for (int nt = 0; nt < 2; ++nt)
            b[nt] = *(const bf16x8*)&PWx1[((kb * 8 + w * 2 + nt) * 64 + lane) * 8];
        #pragma unroll
        for (int mb = 0; mb < 4; ++mb)
            #pragma unroll
            for (int nt = 0; nt < 2; ++nt)
                acc3[mb][nt] = __builtin_amdgcn_mfma_f32_16x16x32_bf16(
                    a[mb], b[nt], acc3[mb][nt], 0, 0, 0);
    }
    float p[4][4];
    {
        #pragma unroll
        for (int mb = 0; mb < 4; ++mb)
            #pragma unroll
            for (int r = 0; r < 4; ++r)
                p[mb][r] = silu_f(acc3[mb][0][r]) * w2.x +
                           silu_f(acc3[mb][1][r]) * w2.y;
        #pragma unroll
        for (int off = 8; off >= 1; off >>= 1)
            #pragma unroll
            for (int mb = 0; mb < 4; ++mb)
                #pragma unroll
                for (int r = 0; r < 4; ++r)
                    p[mb][r] += __shfl_xor(p[mb][r], off, 64);
    }
    __syncthreads();   // all sM reads (msg + GEMM3) done -> buf reusable as red

    if (l16 == 0) {
        float* red = reinterpret_cast<float*>(buf);
        #pragma unroll
        for (int mb = 0; mb < 4; ++mb)
            #pragma unroll
            for (int r = 0; r < 4; ++r)
                red[w * 64 + mb * 16 + quad * 4 + r] = p[mb][r];
    }
    __syncthreads();
    if (t < 64) {
        const float* red = reinterpret_cast<const float*>(buf);
        sW[t] = tanh_f(red[t] + red[64 + t] + red[128 + t] + red[192 + t] + bx2[0]);
    }
    __syncthreads();

    // coord: per-wave segmented shuffle reduction
    if (w < 3) {
        const int dstv = sDst[lane];
        float v = sDiff[lane][w] * sW[lane];
        #pragma unroll
        for (int off = 1; off <= 32; off <<= 1) {
            const int   dn = __shfl_down(dstv, off, 64);
            const float vn = __shfl_down(v, off, 64);
            if (lane + off < 64 && dn == dstv) v += vn;
        }
        const int up = __shfl_up(dstv, 1, 64);
        if (lane == 0 || up != dstv)
            atomicAdd(&coord_agg[(size_t)dstv * 3 + w], v);
    }
}

// ============ node kernel (32-row blocks; A from f32 h in-register) ============
__global__ __launch_bounds__(256, 4) void egnn_node_kernel(
    const float* __restrict__ h,
    const float* __restrict__ x, const int* __restrict__ fixed_mask,
    const unsigned short* __restrict__ PWh1, const float* __restrict__ bh1,
    const unsigned short* __restrict__ PWh2, const float* __restrict__ bh2,
    const float* __restrict__ msg_agg, const float* __restrict__ coord_agg,
    float* __restrict__ out_h, float* __restrict__ out_x)
{
    __shared__ __align__(16) unsigned short sTn[32 * P2];
    const int t  = threadIdx.x;
    const int n0 = blockIdx.x * 32;
    const int lane = t & 63, w = t >> 6;
    const int quad = lane >> 4, l16 = lane & 15;

    if (t < 96) {
        const int ln = t / 3, d3 = t - ln * 3;
        const int n  = n0 + ln;
        if (n < NN) {
            const float add = (fixed_mask[n] != 0) ? 0.0f : coord_agg[(size_t)n*3 + d3];
            out_x[(size_t)n*3 + d3] = x[(size_t)n*3 + d3] + add;
        }
    }

    int nrow[2];
    #pragma unroll
    for (int mb = 0; mb < 2; ++mb) nrow[mb] = min(n0 + mb * 16 + l16, NN - 1);

    // bh1 folded into C-init
    f32x4 acc[2][2];
    #pragma unroll
    for (int nt = 0; nt < 2; ++nt) {
        const float bias = bh1[w * 32 + nt * 16 + l16];
        #pragma unroll
        for (int mb = 0; mb < 2; ++mb)
            acc[mb][nt] = (f32x4){bias, bias, bias, bias};
    }

    #pragma unroll
    for (int kb = 0; kb < 8; ++kb) {
        bf16x8 a[2], b[2];
        if (kb < 4) {
            #pragma unroll
            for (int mb = 0; mb < 2; ++mb)
                a[mb] = ldcvt_bf8(&h[(size_t)nrow[mb] * HD + kb * 32 + quad * 8]);
        } else {
            #pragma unroll
            for (int mb = 0; mb < 2; ++mb)
                a[mb] = ldcvt_bf8(&msg_agg[(size_t)nrow[mb] * HD + (kb - 4) * 32 + quad * 8]);
        }
        #pragma unroll
        for (int nt = 0; nt < 2; ++nt)
            b[nt] = *(const bf16x8*)&PWh1[((kb * 8 + w * 2 + nt) * 64 + lane) * 8];
        #pragma unroll
        for (int mb = 0; mb < 2; ++mb)
            #pragma unroll
            for (int nt = 0; nt < 2; ++nt)
                acc[mb][nt] = __builtin_amdgcn_mfma_f32_16x16x32_bf16(
                    a[mb], b[nt], acc[mb][nt], 0, 0, 0);
    }
    #pragma unroll
    for (int nt = 0; nt < 2; ++nt) {
        const int col = w * 32 + nt * 16 + l16;
        #pragma unroll
        for (int mb = 0; mb < 2; ++mb)
            #pragma unroll
            for (int r = 0; r < 4; ++r) {
                const int row = mb * 16 + quad * 4 + r;
                sTn[row * P2 + col] = f2bf(silu_f(acc[mb][nt][r]));
            }
    }
    __syncthreads();

    // bh2 folded into C-init
    #pragma unroll
    for (int nt = 0; nt < 2; ++nt) {
        const float bias = bh2[w * 32 + nt * 16 + l16];
        #pragma unroll
        for (int mb = 0; mb < 2; ++mb)
            acc[mb][nt] = (f32x4){bias, bias, bias, bias};
    }
    #pragma unroll
    for (int kb = 0; kb < 4; ++kb) {
        bf16x8 a[2], b[2];
        #pragma unroll
        for (int mb = 0; mb < 2; ++mb)
            a[mb] = *(const bf16x8*)&sTn[(mb * 16 + l16) * P2 + kb * 32 + quad * 8];
        #pragma unroll
        for (int nt = 0; nt < 2; ++nt)
            b[nt] = *(const bf16x8*)&PWh2[((kb * 8 + w * 2 + nt) * 64 + lane) * 8];
        #pragma unroll
        for (int mb = 0; mb < 2; ++mb)
            #pragma unroll
            for (int nt = 0; nt < 2; ++nt)
                acc[mb][nt] = __builtin_amdgcn_mfma_f32_16x16x32_bf16(
                    a[mb], b[nt], acc[mb][nt], 0, 0, 0);
    }
    #pragma unroll
    for (int nt = 0; nt < 2; ++nt) {
        const int col = w * 32 + nt * 16 + l16;
        #pragma unroll
        for (int mb = 0; mb < 2; ++mb)
            #pragma unroll
            for (int r = 0; r < 4; ++r) {
                const int row = mb * 16 + quad * 4 + r;
                const int n   = n0 + row;
                if (n < NN)
                    out_h[(size_t)n * HD + col] =
                        h[(size_t)n * HD + col] + acc[mb][nt][r];
            }
    }
}

extern "C" void kernel_launch(void* const* d_in, const int* in_sizes, int n_in,
                              void* d_out, int out_size, void* d_ws, size_t ws_size,
                              hipStream_t stream)
{
    const float* h     = (const float*)d_in[0];
    const float* x     = (const float*)d_in[1];
    const int*   ei    = (const int*)d_in[2];
    const float* eattr = (const float*)d_in[3];
    const int*   fmask = (const int*)d_in[4];
    const float* We1   = (const float*)d_in[5];
    const float* be1   = (const float*)d_in[6];
    const float* We2   = (const float*)d_in[7];
    const float* be2   = (const float*)d_in[8];
    const float* Wx1   = (const float*)d_in[9];
    const float* bx1   = (const float*)d_in[10];
    const float* Wx2   = (const float*)d_in[11];
    const float* bx2   = (const float*)d_in[12];
    const float* Wh1   = (const float*)d_in[13];
    const float* bh1   = (const float*)d_in[14];
    const float* Wh2   = (const float*)d_in[15];
    const float* bh2   = (const float*)d_in[16];

    // ws layout: [msg | coord | cnt] (contiguous, zeroed by ONE memset),
    // then cursor, perm, preS, preD, packed weights. (hb deleted r9.)
    float* msg    = (float*)d_ws;                        // NN*HD
    float* coord  = msg + (size_t)NN * HD;               // NN*3
    int*   cnt    = (int*)(coord + (size_t)NN * 3);      // NN
    int*   cursor = cnt + NN;                            // NN
    int*   perm   = cursor + NN;                         // NE
    unsigned short* preS  = (unsigned short*)(perm + NE);
    unsigned short* preD  = preS + (size_t)NN * HD;
    unsigned short* PWt   = preD + (size_t)NN * HD;
    unsigned short* PWe1m = PWt + S_PWT;
    unsigned short* PWe2  = PWe1m + S_PWE1M;
    unsigned short* PWx1  = PWe2 + S_PW4;
    unsigned short* PWh1  = PWx1 + S_PW4;
    unsigned short* PWh2  = PWh1 + S_PWH1;

    float* out_h = (float*)d_out;
    float* out_x = out_h + (size_t)NN * HD;

    // one wide memset: msg (NN*HD) + coord (NN*3) + cnt (NN) = NN*(HD+4) ints
    hipMemsetAsync(d_ws, 0, (size_t)NN * (HD + 4) * sizeof(int), stream);
    egnn_prep_kernel<<<1024, 256, 0, stream>>>(
        ei, We1, We2, Wx1, Wh1, Wh2,
        PWt, PWe1m, PWe2, PWx1, PWh1, PWh2, cnt);
    egnn_pre_kernel<<<626, 256, 0, stream>>>(h, PWe1m, be1, cnt, cursor, preS, preD);
    egnn_perm_kernel<<<NE / 256, 256, 0, stream>>>(ei, cursor, perm);
    egnn_edge_kernel<<<NE / 64, 256, 0, stream>>>(
        preS, preD, x, ei, eattr, perm, PWt, PWe2, be2, PWx1, bx1,
        Wx2, bx2, msg, coord);
    egnn_node_kernel<<<(NN + 31) / 32, 256, 0, stream>>>(
        h, x, fmask, PWh1, bh1, PWh2, bh2, msg, coord, out_h, out_x);
}

// Round 10
// 364.038 us; speedup vs baseline: 1.0395x; 1.0395x over previous
//
#include <hip/hip_runtime.h>
#include <hip/hip_bf16.h>
#include <math.h>

#define NN   20000
#define NE   640000
#define HD   128
#define EDIM 16
#define KIN  273
#define P2   136      // LDS pitch (ushorts)

#define S_PWT   4096    // We1 tail:   1 kb x 8 nb x 512 (interleaved cols)
#define S_PWE1M 32768   // We1 main:   8 kb x 8 nb x 512 (interleaved cols)
#define S_PW4   16384   // We2/Wx1:    4 kb x 8 nb x 512 (interleaved cols)
#define S_PWH1  32768   // Wh1:        8 kb x 8 nb x 512 (identity cols)
#define S_PWH2  16384   // Wh2:        4 kb x 8 nb x 512 (identity cols)

typedef __bf16 bf16x8 __attribute__((ext_vector_type(8)));
typedef float  f32x4  __attribute__((ext_vector_type(4)));

__device__ __forceinline__ float silu_f(float v) {
    const float e = __expf(-v);
    return v * __builtin_amdgcn_rcpf(1.0f + e);
}
__device__ __forceinline__ float tanh_f(float s) {
    const float e = __expf(2.0f * s);
    return 1.0f - 2.0f * __builtin_amdgcn_rcpf(e + 1.0f);
}
__device__ __forceinline__ unsigned short f2bf(float f) {
    __bf16 b = (__bf16)f;
    return __builtin_bit_cast(unsigned short, b);
}
__device__ __forceinline__ float bf2f(unsigned short u) {
    __bf16 b = __builtin_bit_cast(__bf16, u);
    return (float)b;
}
__device__ __forceinline__ unsigned pack2bf(float a, float b) {
    return (unsigned)f2bf(a) | ((unsigned)f2bf(b) << 16);
}
// load 8 f32 and convert to a bf16x8 MFMA fragment (RNE, same as f2bf)
__device__ __forceinline__ bf16x8 ldcvt_bf8(const float* __restrict__ p) {
    const float4 v0 = ((const float4*)p)[0];
    const float4 v1 = ((const float4*)p)[1];
    bf16x8 av;
    av[0]=(__bf16)v0.x; av[1]=(__bf16)v0.y; av[2]=(__bf16)v0.z; av[3]=(__bf16)v0.w;
    av[4]=(__bf16)v1.x; av[5]=(__bf16)v1.y; av[6]=(__bf16)v1.z; av[7]=(__bf16)v1.w;
    return av;
}

// identity pack: tile (kb,nb): elem[lane*8+j] = W[kb*32+(lane>>4)*8+j][nb*16+(lane&15)]
__device__ __forceinline__ void pack_id(const float* __restrict__ W, int Kreal,
                                        unsigned short* __restrict__ P, int idx) {
    const int f = idx >> 9, r = idx & 511;
    const int lane = r >> 3, j = r & 7;
    const int kb = f >> 3, nb = f & 7;
    const int k = kb * 32 + (lane >> 4) * 8 + j;
    const int n = nb * 16 + (lane & 15);
    P[idx] = f2bf((k < Kreal) ? W[(size_t)k * HD + n] : 0.0f);
}
// interleaved pack: n = (nb>>1)*32 + 2*(lane&15) + (nb&1)
__device__ __forceinline__ void pack_il(const float* __restrict__ W, int Kreal,
                                        unsigned short* __restrict__ P, int idx) {
    const int f = idx >> 9, r = idx & 511;
    const int lane = r >> 3, j = r & 7;
    const int kb = f >> 3, nb = f & 7;
    const int k = kb * 32 + (lane >> 4) * 8 + j;
    const int n = (nb >> 1) * 32 + 2 * (lane & 15) + (nb & 1);
    P[idx] = f2bf((k < Kreal) ? W[(size_t)k * HD + n] : 0.0f);
}

// ===== prep: pack all weights + dst histogram =====
// r10: tail K-order remapped — slots 0..15 = eattr rows (We1 257..272),
// slot 16 = dist row (We1 256), slots 17..31 = zero. Matches the edge
// kernel's sequential eattrB staging.

__global__ void egnn_prep_kernel(
    const int* __restrict__ ei,
    const float* __restrict__ We1, const float* __restrict__ We2,
    const float* __restrict__ Wx1, const float* __restrict__ Wh1,
    const float* __restrict__ Wh2,
    unsigned short* __restrict__ PWt,  unsigned short* __restrict__ PWe1m,
    unsigned short* __restrict__ PWe2, unsigned short* __restrict__ PWx1,
    unsigned short* __restrict__ PWh1, unsigned short* __restrict__ PWh2,
    int* __restrict__ cnt)
{
    const size_t T1 = S_PWT, T2 = T1 + S_PWE1M, T3 = T2 + S_PW4;
    const size_t T4 = T3 + S_PW4, T5 = T4 + S_PWH1, T6 = T5 + S_PWH2;
    const size_t TOT = T6 + NE;
    const size_t stride = (size_t)gridDim.x * blockDim.x;
    for (size_t i = (size_t)blockIdx.x * blockDim.x + threadIdx.x; i < TOT; i += stride) {
        if (i < T1) {   // We1 tail, REORDERED K: kk<16 -> row 257+kk, kk==16 -> row 256
            const int idx = (int)i;
            const int r = idx & 511, nb = idx >> 9;
            const int lane = r >> 3, j = r & 7;
            const int kk = (lane >> 4) * 8 + j;
            const int n = (nb >> 1) * 32 + 2 * (lane & 15) + (nb & 1);
            int wr = -1;
            if (kk < 16) wr = 257 + kk;
            else if (kk == 16) wr = 256;
            PWt[idx] = f2bf((wr >= 0) ? We1[(size_t)wr * HD + n] : 0.0f);
            continue;
        }
        if (i < T2) { pack_il(We1, 256, PWe1m, (int)(i - T1)); continue; }
        if (i < T3) { pack_il(We2, HD, PWe2, (int)(i - T2)); continue; }
        if (i < T4) { pack_il(Wx1, HD, PWx1, (int)(i - T3)); continue; }
        if (i < T5) { pack_id(Wh1, 2 * HD, PWh1, (int)(i - T4)); continue; }
        if (i < T6) { pack_id(Wh2, HD, PWh2, (int)(i - T5)); continue; }
        atomicAdd(&cnt[ei[NE + (i - T6)]], 1);   // histogram
    }
}

// ====== preGEMM (blocks 0..624, 32 rows each) + scan (block 625) ======
__global__ __launch_bounds__(256, 4) void egnn_pre_kernel(
    const float* __restrict__ h,
    const unsigned short* __restrict__ PWe1m, const float* __restrict__ be1,
    const int* __restrict__ cnt, int* __restrict__ cursor,
    unsigned short* __restrict__ preS, unsigned short* __restrict__ preD)
{
    const int t = threadIdx.x;
    if (blockIdx.x == 625) {        // exclusive scan of cnt -> cursor (SEG=79)
        __shared__ int ls[256];
        const int base = t * 79;
        int c[79];
        int s = 0;
        for (int i = 0; i < 79; ++i) {
            const int idx = base + i;
            c[i] = (idx < NN) ? cnt[idx] : 0;
            s += c[i];
        }
        ls[t] = s;
        __syncthreads();
        int v = s;
        for (int off = 1; off < 256; off <<= 1) {
            const int u = (t >= off) ? ls[t - off] : 0;
            __syncthreads();
            v += u;
            ls[t] = v;
            __syncthreads();
        }
        int run = v - s;
        for (int i = 0; i < 79; ++i) {
            const int idx = base + i;
            if (idx < NN) { cursor[idx] = run; run += c[i]; }
        }
        return;
    }
    // preS = h@We1[0:128]; preD = h@We1[128:256] + be1 (interleaved col order)
    const int n0 = blockIdx.x * 32;
    const int lane = t & 63, w = t >> 6;
    const int quad = lane >> 4, l16 = lane & 15;
    int arow[2];
    #pragma unroll
    for (int mb = 0; mb < 2; ++mb) arow[mb] = min(n0 + mb * 16 + l16, NN - 1);

    f32x4 accS[2][2], accD[2][2];
    #pragma unroll
    for (int mb = 0; mb < 2; ++mb)
        #pragma unroll
        for (int nt = 0; nt < 2; ++nt) {
            accS[mb][nt] = (f32x4){0.f,0.f,0.f,0.f};
            accD[mb][nt] = (f32x4){0.f,0.f,0.f,0.f};
        }
    #pragma unroll
    for (int kb = 0; kb < 4; ++kb) {
        bf16x8 a[2], bS[2], bD[2];
        #pragma unroll
        for (int mb = 0; mb < 2; ++mb)
            a[mb] = ldcvt_bf8(&h[(size_t)arow[mb] * HD + kb * 32 + quad * 8]);
        #pragma unroll
        for (int nt = 0; nt < 2; ++nt) {
            bS[nt] = *(const bf16x8*)&PWe1m[((kb * 8 + w * 2 + nt) * 64 + lane) * 8];
            bD[nt] = *(const bf16x8*)&PWe1m[(((4 + kb) * 8 + w * 2 + nt) * 64 + lane) * 8];
        }
        #pragma unroll
        for (int mb = 0; mb < 2; ++mb)
            #pragma unroll
            for (int nt = 0; nt < 2; ++nt) {
                accS[mb][nt] = __builtin_amdgcn_mfma_f32_16x16x32_bf16(
                    a[mb], bS[nt], accS[mb][nt], 0, 0, 0);
                accD[mb][nt] = __builtin_amdgcn_mfma_f32_16x16x32_bf16(
                    a[mb], bD[nt], accD[mb][nt], 0, 0, 0);
            }
    }
    const int cb = w * 32 + 2 * l16;
    const float2 b1 = *(const float2*)&be1[cb];
    #pragma unroll
    for (int mb = 0; mb < 2; ++mb)
        #pragma unroll
        for (int r = 0; r < 4; ++r) {
            const int n = n0 + mb * 16 + quad * 4 + r;
            if (n < NN) {
                *(unsigned*)&preS[(size_t)n * HD + cb] =
                    pack2bf(accS[mb][0][r], accS[mb][1][r]);
                *(unsigned*)&preD[(size_t)n * HD + cb] =
                    pack2bf(accD[mb][0][r] + b1.x, accD[mb][1][r] + b1.y);
            }
        }
}

// ============ perm: apply the counting-sort permutation to the PAYLOAD ============
// r10: instead of perm[pos]=e (and edge re-gathering ei/eattr through it),
// write sdP[pos]=(src,dst) and eattrB[pos]=bf16 row. Reads here are fully
// sequential (ei 5MB + eattr 41MB); scattered writes (25.6MB, L2-resident,
// every line fully covered) replace the edge kernel's scattered reads.
__global__ void egnn_perm_kernel(const int* __restrict__ ei,
                                 const float* __restrict__ eattr,
                                 int* __restrict__ cursor,
                                 int2* __restrict__ sdP,
                                 unsigned short* __restrict__ eattrB) {
    const int e = blockIdx.x * 256 + threadIdx.x;
    const int s = ei[e];
    const int d = ei[NE + e];
    const int pos = atomicAdd(&cursor[d], 1);
    sdP[pos] = make_int2(s, d);
    const float4 v0 = ((const float4*)eattr)[(size_t)e * 4 + 0];
    const float4 v1 = ((const float4*)eattr)[(size_t)e * 4 + 1];
    const float4 v2 = ((const float4*)eattr)[(size_t)e * 4 + 2];
    const float4 v3 = ((const float4*)eattr)[(size_t)e * 4 + 3];
    uint4 a, b;
    a.x = pack2bf(v0.x, v0.y); a.y = pack2bf(v0.z, v0.w);
    a.z = pack2bf(v1.x, v1.y); a.w = pack2bf(v1.z, v1.w);
    b.x = pack2bf(v2.x, v2.y); b.y = pack2bf(v2.z, v2.w);
    b.z = pack2bf(v3.x, v3.y); b.w = pack2bf(v3.z, v3.w);
    ((uint4*)eattrB)[(size_t)pos * 2 + 0] = a;
    ((uint4*)eattrB)[(size_t)pos * 2 + 1] = b;
}

// ===== edge kernel: r0 compute structure (gather preC, 6 blocks/CU, no
// swizzle). A/B ledger: r1 swizzle / r2 8blk / r3 MFMA-inject / r4 NT all
// REVERTED (see prior rounds). r10: perm/ei/eattr scattered reads replaced
// by sequential sdP + eattrB (payload pre-permuted in perm kernel); tail
// staged as coalesced 16B copies; one fewer barrier.
__global__ __launch_bounds__(256, 6) void egnn_edge_kernel(
    const unsigned short* __restrict__ preS, const unsigned short* __restrict__ preD,
    const float* __restrict__ x,
    const int2* __restrict__ sdP, const unsigned short* __restrict__ eattrB,
    const unsigned short* __restrict__ PWt,
    const unsigned short* __restrict__ PWe2, const float* __restrict__ be2,
    const unsigned short* __restrict__ PWx1, const float* __restrict__ bx1,
    const float* __restrict__ Wx2, const float* __restrict__ bx2,
    float* __restrict__ msg_agg, float* __restrict__ coord_agg)
{
    __shared__ __align__(16) unsigned short buf[64 * P2];   // tail -> sT -> sM -> red
    __shared__ int   sSrc[64], sDst[64];
    __shared__ float sDiff[64][3];
    __shared__ float sW[64];

    const int t  = threadIdx.x;
    const int e0 = blockIdx.x * 64;
    unsigned short* tail = buf;   // [64][32] in first 4 KB

    if (t < 64) {
        const int2 sd = sdP[e0 + t];
        const int s = sd.x, d = sd.y;
        sSrc[t] = s; sDst[t] = d;
        const float dx = x[s*3+0] - x[d*3+0];
        const float dy = x[s*3+1] - x[d*3+1];
        const float dz = x[s*3+2] - x[d*3+2];
        sDiff[t][0] = dx; sDiff[t][1] = dy; sDiff[t][2] = dz;
        tail[t * 32 + 16] = f2bf((dx*dx + dy*dy + dz*dz) * 0.01f);   // dist slot
    }
    // tail cols 0..15 <- eattrB (sequential 16B loads), 17..31 <- 0
    {
        const int eL = t >> 2, q = t & 3;
        if (q < 2) {
            const uint4 v = ((const uint4*)eattrB)[(size_t)(e0 + eL) * 2 + q];
            *(uint4*)&tail[eL * 32 + q * 8] = v;
        } else if (q == 2) {
            #pragma unroll
            for (int c = 17; c < 24; ++c) tail[eL * 32 + c] = 0;
        } else {
            #pragma unroll
            for (int c = 24; c < 32; ++c) tail[eL * 32 + c] = 0;
        }
    }
    __syncthreads();

    const int lane = t & 63;
    const int w    = t >> 6;
    const int quad = lane >> 4;
    const int l16  = lane & 15;
    const int cb   = w * 32 + 2 * l16;

    // preC = preS[src] + preD[dst] (preD includes be1)
    f32x4 preC[4][2];
    #pragma unroll
    for (int mb = 0; mb < 4; ++mb)
        #pragma unroll
        for (int r = 0; r < 4; ++r) {
            const int row = mb * 16 + quad * 4 + r;
            const unsigned us = *(const unsigned*)&preS[(size_t)sSrc[row] * HD + cb];
            const unsigned ud = *(const unsigned*)&preD[(size_t)sDst[row] * HD + cb];
            preC[mb][0][r] = bf2f((unsigned short)(us & 0xffff)) +
                             bf2f((unsigned short)(ud & 0xffff));
            preC[mb][1][r] = bf2f((unsigned short)(us >> 16)) +
                             bf2f((unsigned short)(ud >> 16));
        }

    // GEMM1 (K=32 tail), C init = preC
    f32x4 acc1[4][2];
    {
        bf16x8 a[4], b[2];
        #pragma unroll
        for (int mb = 0; mb < 4; ++mb)
            a[mb] = *(const bf16x8*)&tail[(mb * 16 + l16) * 32 + quad * 8];
        #pragma unroll
        for (int nt = 0; nt < 2; ++nt)
            b[nt] = *(const bf16x8*)&PWt[((w * 2 + nt) * 64 + lane) * 8];
        #pragma unroll
        for (int mb = 0; mb < 4; ++mb)
            #pragma unroll
            for (int nt = 0; nt < 2; ++nt)
                acc1[mb][nt] = __builtin_amdgcn_mfma_f32_16x16x32_bf16(
                    a[mb], b[nt], preC[mb][nt], 0, 0, 0);
    }
    __syncthreads();   // all tail reads done -> buf reusable as sT

    #pragma unroll
    for (int mb = 0; mb < 4; ++mb)
        #pragma unroll
        for (int r = 0; r < 4; ++r) {
            const int row = mb * 16 + quad * 4 + r;
            *(unsigned*)&buf[row * P2 + cb] =
                pack2bf(silu_f(acc1[mb][0][r]), silu_f(acc1[mb][1][r]));
        }
    __syncthreads();

    // GEMM2: t1 @ We2  (be2 folded into C-init)
    const float2 b2 = *(const float2*)&be2[cb];
    f32x4 acc2[4][2];
    #pragma unroll
    for (int mb = 0; mb < 4; ++mb) {
        acc2[mb][0] = (f32x4){b2.x, b2.x, b2.x, b2.x};
        acc2[mb][1] = (f32x4){b2.y, b2.y, b2.y, b2.y};
    }
    #pragma unroll
    for (int kb = 0; kb < 4; ++kb) {
        bf16x8 a[4], b[2];
        #pragma unroll
        for (int mb = 0; mb < 4; ++mb)
            a[mb] = *(const bf16x8*)&buf[(mb * 16 + l16) * P2 + kb * 32 + quad * 8];
        #pragma unroll
        for (int nt = 0; nt < 2; ++nt)
            b[nt] = *(const bf16x8*)&PWe2[((kb * 8 + w * 2 + nt) * 64 + lane) * 8];
        #pragma unroll
        for (int mb = 0; mb < 4; ++mb)
            #pragma unroll
            for (int nt = 0; nt < 2; ++nt)
                acc2[mb][nt] = __builtin_amdgcn_mfma_f32_16x16x32_bf16(
                    a[mb], b[nt], acc2[mb][nt], 0, 0, 0);
    }
    __syncthreads();   // all sT reads done -> buf reusable as sM

    {
        #pragma unroll
        for (int mb = 0; mb < 4; ++mb)
            #pragma unroll
            for (int r = 0; r < 4; ++r) {
                const int row = mb * 16 + quad * 4 + r;
                *(unsigned*)&buf[row * P2 + cb] =
                    pack2bf(silu_f(acc2[mb][0][r]),
                            silu_f(acc2[mb][1][r]));
            }
    }
    __syncthreads();

    // msg: dst-sorted run reduction (reads buf as sM)
    {
        const int cp = t & 63;
        const int r0 = (t >> 6) * 16;
        float a0 = 0.0f, a1 = 0.0f;
        #pragma unroll 4
        for (int r = 0; r < 16; ++r) {
            const int row = r0 + r;
            const int d   = sDst[row];
            const unsigned u = *(const unsigned*)&buf[row * P2 + 2 * cp];
            a0 += bf2f((unsigned short)(u & 0xffff));
            a1 += bf2f((unsigned short)(u >> 16));
            const bool flush = (r == 15) || (sDst[row + 1] != d);
            if (flush) {
                atomicAdd(&msg_agg[(size_t)d * HD + 2 * cp], a0);
                atomicAdd(&msg_agg[(size_t)d * HD + 2 * cp + 1], a1);
                a0 = 0.0f; a1 = 0.0f;
            }
        }
    }

    // GEMM3: m @ Wx1 (reads buf as sM; bx1 folded into C-init)
    const float2 bx = *(const float2*)&bx1[cb];
    const float2 w2 = *(const float2*)&Wx2[cb];
    f32x4 acc3[4][2];
    #pragma unroll
    for (int mb = 0; mb < 4; ++mb) {
        acc3[mb][0] = (f32x4){bx.x, bx.x, bx.x, bx.x};
        acc3[mb][1] = (f32x4){bx.y, bx.y, bx.y, bx.y};
    }
    #pragma unroll
    for (int kb = 0; kb < 4; ++kb) {
        bf16x8 a[4], b[2];
        #pragma unroll
        for (int mb = 0; mb < 4; ++mb)
            a[mb] = *(const bf16x8*)&buf[(mb * 16 + l16) * P2 + kb * 32 + quad * 8];
        #pragma unroll
        for (int nt = 0; nt < 2; ++nt)
            b[nt] = *(const bf16x8*)&PWx1[((kb * 8 + w * 2 + nt) * 64 + lane) * 8];
        #pragma unroll
        for (int mb = 0; mb < 4; ++mb)
            #pragma unroll
            for (int nt = 0; nt < 2; ++nt)
                acc3[mb][nt] = __builtin_amdgcn_mfma_f32_16x16x32_bf16(
                    a[mb], b[nt], acc3[mb][nt], 0, 0, 0);
    }
    float p[4][4];
    {
        #pragma unroll
        for (int mb = 0; mb < 4; ++mb)
            #pragma unroll
            for (int r = 0; r < 4; ++r)
                p[mb][r] = silu_f(acc3[mb][0][r]) * w2.x +
                           silu_f(acc3[mb][1][r]) * w2.y;
        #pragma unroll
        for (int off = 8; off >= 1; off >>= 1)
            #pragma unroll
            for (int mb = 0; mb < 4; ++mb)
                #pragma unroll
                for (int r = 0; r < 4; ++r)
                    p[mb][r] += __shfl_xor(p[mb][r], off, 64);
    }
    __syncthreads();   // all sM reads (msg + GEMM3) done -> buf reusable as red

    if (l16 == 0) {
        float* red = reinterpret_cast<float*>(buf);
        #pragma unroll
        for (int mb = 0; mb < 4; ++mb)
            #pragma unroll
            for (int r = 0; r < 4; ++r)
                red[w * 64 + mb * 16 + quad * 4 + r] = p[mb][r];
    }
    __syncthreads();
    if (t < 64) {
        const float* red = reinterpret_cast<const float*>(buf);
        sW[t] = tanh_f(red[t] + red[64 + t] + red[128 + t] + red[192 + t] + bx2[0]);
    }
    __syncthreads();

    // coord: per-wave segmented shuffle reduction
    if (w < 3) {
        const int dstv = sDst[lane];
        float v = sDiff[lane][w] * sW[lane];
        #pragma unroll
        for (int off = 1; off <= 32; off <<= 1) {
            const int   dn = __shfl_down(dstv, off, 64);
            const float vn = __shfl_down(v, off, 64);
            if (lane + off < 64 && dn == dstv) v += vn;
        }
        const int up = __shfl_up(dstv, 1, 64);
        if (lane == 0 || up != dstv)
            atomicAdd(&coord_agg[(size_t)dstv * 3 + w], v);
    }
}

// ============ node kernel (32-row blocks; A from f32 h in-register) ============
__global__ __launch_bounds__(256, 4) void egnn_node_kernel(
    const float* __restrict__ h,
    const float* __restrict__ x, const int* __restrict__ fixed_mask,
    const unsigned short* __restrict__ PWh1, const float* __restrict__ bh1,
    const unsigned short* __restrict__ PWh2, const float* __restrict__ bh2,
    const float* __restrict__ msg_agg, const float* __restrict__ coord_agg,
    float* __restrict__ out_h, float* __restrict__ out_x)
{
    __shared__ __align__(16) unsigned short sTn[32 * P2];
    const int t  = threadIdx.x;
    const int n0 = blockIdx.x * 32;
    const int lane = t & 63, w = t >> 6;
    const int quad = lane >> 4, l16 = lane & 15;

    if (t < 96) {
        const int ln = t / 3, d3 = t - ln * 3;
        const int n  = n0 + ln;
        if (n < NN) {
            const float add = (fixed_mask[n] != 0) ? 0.0f : coord_agg[(size_t)n*3 + d3];
            out_x[(size_t)n*3 + d3] = x[(size_t)n*3 + d3] + add;
        }
    }

    int nrow[2];
    #pragma unroll
    for (int mb = 0; mb < 2; ++mb) nrow[mb] = min(n0 + mb * 16 + l16, NN - 1);

    // bh1 folded into C-init
    f32x4 acc[2][2];
    #pragma unroll
    for (int nt = 0; nt < 2; ++nt) {
        const float bias = bh1[w * 32 + nt * 16 + l16];
        #pragma unroll
        for (int mb = 0; mb < 2; ++mb)
            acc[mb][nt] = (f32x4){bias, bias, bias, bias};
    }

    #pragma unroll
    for (int kb = 0; kb < 8; ++kb) {
        bf16x8 a[2], b[2];
        if (kb < 4) {
            #pragma unroll
            for (int mb = 0; mb < 2; ++mb)
                a[mb] = ldcvt_bf8(&h[(size_t)nrow[mb] * HD + kb * 32 + quad * 8]);
        } else {
            #pragma unroll
            for (int mb = 0; mb < 2; ++mb)
                a[mb] = ldcvt_bf8(&msg_agg[(size_t)nrow[mb] * HD + (kb - 4) * 32 + quad * 8]);
        }
        #pragma unroll
        for (int nt = 0; nt < 2; ++nt)
            b[nt] = *(const bf16x8*)&PWh1[((kb * 8 + w * 2 + nt) * 64 + lane) * 8];
        #pragma unroll
        for (int mb = 0; mb < 2; ++mb)
            #pragma unroll
            for (int nt = 0; nt < 2; ++nt)
                acc[mb][nt] = __builtin_amdgcn_mfma_f32_16x16x32_bf16(
                    a[mb], b[nt], acc[mb][nt], 0, 0, 0);
    }
    #pragma unroll
    for (int nt = 0; nt < 2; ++nt) {
        const int col = w * 32 + nt * 16 + l16;
        #pragma unroll
        for (int mb = 0; mb < 2; ++mb)
            #pragma unroll
            for (int r = 0; r < 4; ++r) {
                const int row = mb * 16 + quad * 4 + r;
                sTn[row * P2 + col] = f2bf(silu_f(acc[mb][nt][r]));
            }
    }
    __syncthreads();

    // bh2 folded into C-init
    #pragma unroll
    for (int nt = 0; nt < 2; ++nt) {
        const float bias = bh2[w * 32 + nt * 16 + l16];
        #pragma unroll
        for (int mb = 0; mb < 2; ++mb)
            acc[mb][nt] = (f32x4){bias, bias, bias, bias};
    }
    #pragma unroll
    for (int kb = 0; kb < 4; ++kb) {
        bf16x8 a[2], b[2];
        #pragma unroll
        for (int mb = 0; mb < 2; ++mb)
            a[mb] = *(const bf16x8*)&sTn[(mb * 16 + l16) * P2 + kb * 32 + quad * 8];
        #pragma unroll
        for (int nt = 0; nt < 2; ++nt)
            b[nt] = *(const bf16x8*)&PWh2[((kb * 8 + w * 2 + nt) * 64 + lane) * 8];
        #pragma unroll
        for (int mb = 0; mb < 2; ++mb)
            #pragma unroll
            for (int nt = 0; nt < 2; ++nt)
                acc[mb][nt] = __builtin_amdgcn_mfma_f32_16x16x32_bf16(
                    a[mb], b[nt], acc[mb][nt], 0, 0, 0);
    }
    #pragma unroll
    for (int nt = 0; nt < 2; ++nt) {
        const int col = w * 32 + nt * 16 + l16;
        #pragma unroll
        for (int mb = 0; mb < 2; ++mb)
            #pragma unroll
            for (int r = 0; r < 4; ++r) {
                const int row = mb * 16 + quad * 4 + r;
                const int n   = n0 + row;
                if (n < NN)
                    out_h[(size_t)n * HD + col] =
                        h[(size_t)n * HD + col] + acc[mb][nt][r];
            }
    }
}

extern "C" void kernel_launch(void* const* d_in, const int* in_sizes, int n_in,
                              void* d_out, int out_size, void* d_ws, size_t ws_size,
                              hipStream_t stream)
{
    const float* h     = (const float*)d_in[0];
    const float* x     = (const float*)d_in[1];
    const int*   ei    = (const int*)d_in[2];
    const float* eattr = (const float*)d_in[3];
    const int*   fmask = (const int*)d_in[4];
    const float* We1   = (const float*)d_in[5];
    const float* be1   = (const float*)d_in[6];
    const float* We2   = (const float*)d_in[7];
    const float* be2   = (const float*)d_in[8];
    const float* Wx1   = (const float*)d_in[9];
    const float* bx1   = (const float*)d_in[10];
    const float* Wx2   = (const float*)d_in[11];
    const float* bx2   = (const float*)d_in[12];
    const float* Wh1   = (const float*)d_in[13];
    const float* bh1   = (const float*)d_in[14];
    const float* Wh2   = (const float*)d_in[15];
    const float* bh2   = (const float*)d_in[16];

    // ws layout: [msg | coord | cnt] (contiguous, zeroed by ONE memset),
    // then cursor, sdP (int2/edge), eattrB (bf16 row/edge), preS, preD, packs.
    float* msg    = (float*)d_ws;                        // NN*HD
    float* coord  = msg + (size_t)NN * HD;               // NN*3
    int*   cnt    = (int*)(coord + (size_t)NN * 3);      // NN
    int*   cursor = cnt + NN;                            // NN
    int2*  sdP    = (int2*)(cursor + NN);                // NE int2
    unsigned short* eattrB = (unsigned short*)(sdP + NE);   // NE*16
    unsigned short* preS  = eattrB + (size_t)NE * 16;
    unsigned short* preD  = preS + (size_t)NN * HD;
    unsigned short* PWt   = preD + (size_t)NN * HD;
    unsigned short* PWe1m = PWt + S_PWT;
    unsigned short* PWe2  = PWe1m + S_PWE1M;
    unsigned short* PWx1  = PWe2 + S_PW4;
    unsigned short* PWh1  = PWx1 + S_PW4;
    unsigned short* PWh2  = PWh1 + S_PWH1;

    float* out_h = (float*)d_out;
    float* out_x = out_h + (size_t)NN * HD;

    // one wide memset: msg (NN*HD) + coord (NN*3) + cnt (NN) = NN*(HD+4) ints
    hipMemsetAsync(d_ws, 0, (size_t)NN * (HD + 4) * sizeof(int), stream);
    egnn_prep_kernel<<<1024, 256, 0, stream>>>(
        ei, We1, We2, Wx1, Wh1, Wh2,
        PWt, PWe1m, PWe2, PWx1, PWh1, PWh2, cnt);
    egnn_pre_kernel<<<626, 256, 0, stream>>>(h, PWe1m, be1, cnt, cursor, preS, preD);
    egnn_perm_kernel<<<NE / 256, 256, 0, stream>>>(ei, eattr, cursor, sdP, eattrB);
    egnn_edge_kernel<<<NE / 64, 256, 0, stream>>>(
        preS, preD, x, sdP, eattrB, PWt, PWe2, be2, PWx1, bx1,
        Wx2, bx2, msg, coord);
    egnn_node_kernel<<<(NN + 31) / 32, 256, 0, stream>>>(
        h, x, fmask, PWh1, bh1, PWh2, bh2, msg, coord, out_h, out_x);
}